// Round 10
// baseline (2910.876 us; speedup 1.0000x reference)
//
#include <hip/hip_runtime.h>
#include <stdint.h>

#define DIM 768
#define NL 13
#define NH 12
#define VOCAB 50257
#define SEQ 512
#define BATCH 4
#define HID 3072
#define HD 64
#define NTOK (BATCH*SEQ)   // 2048
#define BHB (BATCH*NH)     // 48 batched heads

typedef unsigned short u16;
typedef __attribute__((ext_vector_type(8))) __bf16 bf16x8;
typedef __attribute__((ext_vector_type(4))) float f32x4;

#define ASM_VMCNT(N) asm volatile("s_waitcnt vmcnt(" #N ")" ::: "memory")
#define ASM_LGKM0()  asm volatile("s_waitcnt lgkmcnt(0)" ::: "memory")

__device__ __forceinline__ u16 f2bf(float f) {
    union { float f; uint32_t u; } v; v.f = f;
    uint32_t u = v.u;
    return (u16)((u + 0x7FFFu + ((u >> 16) & 1u)) >> 16);   // RNE
}

__device__ __forceinline__ void gl2lds16(const void* g, void* l) {
    // async global->LDS, 16B/lane; LDS dest = wave-uniform base + lane*16
    __builtin_amdgcn_global_load_lds((const __attribute__((address_space(1))) void*)g,
                                     (__attribute__((address_space(3))) void*)l,
                                     16, 0, 0);
}

__device__ __forceinline__ float gelu_tanh(float x) {
    // tanh(y) = 1 - 2/(exp(2y)+1) via HW v_exp_f32 (no tanh instruction on gfx950)
    const float y = 0.7978845608028654f * (x + 0.044715f * x * x * x);
    const float t = 1.0f - 2.0f / (__expf(2.0f * y) + 1.0f);
    return 0.5f * x * (1.0f + t);
}

__device__ __forceinline__ void xcd_remap(int& bx, int& by) {
    const int gx = gridDim.x;
    const int nwg = gx * gridDim.y;
    const int orig = by * gx + bx;
    const int xcd = orig & 7;
    const int q = nwg >> 3, r = nwg & 7;
    const int wg = (xcd < r ? xcd * (q + 1) : r * (q + 1) + (xcd - r) * q) + (orig >> 3);
    bx = wg % gx; by = wg / gx;
}

// ---------------------------------------------------------------------------
// Shared epilogue.
// EPI: 0 plain f32 (col-bound checked), 1 qkv scatter, 3 f32 + bias + residual,
//      4 gelu -> bf16, 5 f32 atomic accumulate (split-K; resid pre-resident in
//      out0; bias added exactly once by the z==0 block)
// ---------------------------------------------------------------------------
template<int EPI>
__device__ __forceinline__ void epi_store(float v, int r, int c, int N, int z, long sC,
                                          const float* bias, const float* resid,
                                          void* out0, void* out1, void* out2)
{
    if constexpr (EPI == 0) {
        if (c < N) ((float*)out0)[(long)z * sC + (long)r * N + c] = v;
    } else if constexpr (EPI == 1) {
        v += bias[c];
        const int part = c / DIM;
        const int cc = c - part * DIM;
        const int hh = cc >> 6, d = cc & 63;
        const int b = r >> 9, t = r & 511;
        const int bh = b * NH + hh;
        if (part == 0)      ((u16*)out0)[((long)bh * SEQ + t) * HD + d] = f2bf(v);
        else if (part == 1) ((u16*)out1)[((long)bh * SEQ + t) * HD + d] = f2bf(v);
        else                ((u16*)out2)[((long)bh * HD + d) * SEQ + t] = f2bf(v);
    } else if constexpr (EPI == 3) {
        if (bias) v += bias[c];
        v += resid[(long)r * N + c];
        ((float*)out0)[(long)r * N + c] = v;
    } else if constexpr (EPI == 5) {
        if (bias && z == 0) v += bias[c];
        atomicAdd(&((float*)out0)[(long)r * N + c], v);
    } else {
        ((u16*)out0)[(long)r * N + c] = f2bf(gelu_tanh(v));
    }
}

// ---------------------------------------------------------------------------
// Head GEMM: 128 x (WN*32) tile, BK=32, depth-2 counted-vmcnt pipeline.
// WN=4 kept: m112 measured 128^2 (912 TF) > 128x256 (823) at this structure.
// ---------------------------------------------------------------------------
template<int WN, int EPI>
__global__ __launch_bounds__(256)
void gemm_bt(const u16* __restrict__ A, const u16* __restrict__ B,
             const float* __restrict__ bias, const float* __restrict__ resid,
             void* __restrict__ out0, void* __restrict__ out1, void* __restrict__ out2,
             int M, int N, int K, long sA, long sB, long sC)
{
    constexpr int TN = WN * 32;
    constexpr int NBG = TN / 64;                   // B staging groups of 64 rows
    __shared__ __align__(16) u16 As[2 * 128 * 32];
    __shared__ __align__(16) u16 Bs[2 * TN * 32];

    const int tid  = threadIdx.x;
    const int wave = tid >> 6;
    const int lane = tid & 63;
    const int quad = lane >> 4;
    const int l16  = lane & 15;
    const int wm   = wave >> 1;
    const int wn   = wave & 1;

    int bx = blockIdx.x, by = blockIdx.y;
    xcd_remap(bx, by);

    const int m0 = bx * 128;
    const int n0 = by * TN;
    const int z  = blockIdx.z;

    const u16* Ab = A + (long)z * sA;
    const u16* Bb = B + (long)z * sB;

    const int srow = tid >> 2;          // 0..63
    const int scol = ((tid & 3) ^ ((srow >> 1) & 3)) * 8;   // pre-swizzled k-chunk

    const long aoff0 = (long)(m0 + srow) * K + scol;
    const long aoff1 = (long)(m0 + 64 + srow) * K + scol;
    long boff[NBG];
    #pragma unroll
    for (int g = 0; g < NBG; g++) {
        int br = n0 + g * 64 + srow; if (br > N - 1) br = N - 1;
        boff[g] = (long)br * K + scol;
    }

    auto stage = [&](int b, int k0) {
        gl2lds16(Ab + aoff0 + k0, As + b * 4096 + wave * 512);
        gl2lds16(Ab + aoff1 + k0, As + b * 4096 + 2048 + wave * 512);
        #pragma unroll
        for (int g = 0; g < NBG; g++)
            gl2lds16(Bb + boff[g] + k0, Bs + b * (TN * 32) + g * 2048 + wave * 512);
    };

    f32x4 acc[4][WN];
    #pragma unroll
    for (int i = 0; i < 4; i++)
        #pragma unroll
        for (int j = 0; j < WN; j++)
            acc[i][j] = (f32x4){0.f, 0.f, 0.f, 0.f};

    const int sq8 = (quad ^ ((l16 >> 1) & 3)) * 8;
    const int arow = (wm * 64 + l16) * 32 + sq8;
    const int brow = (wn * (WN * 16) + l16) * 32 + sq8;

    stage(0, 0);
    if (K > 32) stage(1, 32);

    int cur = 0;
    for (int k0 = 0; k0 < K; k0 += 32) {
        // land step k0's loads; step k0+32's (4 newest) may stay in flight
        if (k0 + 32 < K) ASM_VMCNT(4); else ASM_VMCNT(0);
        __builtin_amdgcn_s_barrier();

        const u16* Ar = As + cur * 4096;
        const u16* Br = Bs + cur * (TN * 32);
        bf16x8 af[4], bfr[WN];
        #pragma unroll
        for (int i = 0; i < 4; i++)
            af[i] = *(const bf16x8*)&Ar[arow + i * 512];
        #pragma unroll
        for (int j = 0; j < WN; j++)
            bfr[j] = *(const bf16x8*)&Br[brow + j * 512];
        ASM_LGKM0();                       // own reads done before signalling
        __builtin_amdgcn_s_barrier();      // all waves done reading buf cur
        if (k0 + 64 < K) stage(cur, k0 + 64);   // restage 2 steps ahead

        #pragma unroll
        for (int i = 0; i < 4; i++)
            #pragma unroll
            for (int j = 0; j < WN; j++)
                acc[i][j] = __builtin_amdgcn_mfma_f32_16x16x32_bf16(af[i], bfr[j], acc[i][j], 0, 0, 0);

        cur ^= 1;
    }

    const int rbase = m0 + wm * 64;
    const int cbase = n0 + wn * (WN * 16);
    #pragma unroll
    for (int i = 0; i < 4; i++)
        #pragma unroll
        for (int j = 0; j < WN; j++)
            #pragma unroll
            for (int rg = 0; rg < 4; rg++)
                epi_store<EPI>(acc[i][j][rg], rbase + i * 16 + quad * 4 + rg,
                               cbase + j * 16 + l16, N, z, sC, bias, resid, out0, out1, out2);
}

// ---------------------------------------------------------------------------
// Layer GEMM: 64 x (WN*32) tile, BK=64, depth-2 counted-vmcnt pipeline.
// Split-K via blockIdx.z (EPI=5 atomic accumulate, bias at z==0).
// Requires M%64==0, N%TN==0, K%64==0.
// ---------------------------------------------------------------------------
template<int WN, int EPI>
__global__ __launch_bounds__(256)
void gemm64(const u16* __restrict__ A, const u16* __restrict__ B,
            const float* __restrict__ bias, const float* __restrict__ resid,
            void* __restrict__ out0, void* __restrict__ out1, void* __restrict__ out2,
            int M, int N, int K, int Kstride)
{
    constexpr int TN = WN * 32;
    constexpr int NC = TN / 32;                    // B staging sub-blocks of 32 rows
    __shared__ __align__(16) u16 As[2 * 64 * 64];  // 16 KB
    __shared__ __align__(16) u16 Bs[2 * TN * 64];  // 32 or 16 KB

    const int tid  = threadIdx.x;
    const int wave = tid >> 6;
    const int lane = tid & 63;
    const int quad = lane >> 4;
    const int l16  = lane & 15;
    const int wm   = wave >> 1;
    const int wn   = wave & 1;

    int bx = blockIdx.x, by = blockIdx.y;
    xcd_remap(bx, by);
    const int m0 = bx * 64;
    const int n0 = by * TN;
    const int koff = blockIdx.z * K;

    // staging geometry: row = c*32 + (tid>>3), chunk = tid&7 (8 elems / 16 B)
    const int srow = tid >> 3;                       // 0..31
    const int sch  = ((tid & 7) ^ (srow & 7)) * 8;   // swizzled chunk (elems)
    u16* const asw = As + wave * 512;                // wave*8 rows * 64
    u16* const bsw = Bs + wave * 512;

    const long aoff = (long)(m0 + srow) * Kstride + koff + sch;
    const long boff = (long)(n0 + srow) * Kstride + koff + sch;

    auto stageA = [&](int b, int k0) {
        #pragma unroll
        for (int c = 0; c < 2; c++)
            gl2lds16(A + aoff + (long)c * 32 * Kstride + k0, asw + b * 4096 + c * 2048);
    };
    auto stageB = [&](int b, int k0) {
        #pragma unroll
        for (int c = 0; c < NC; c++)
            gl2lds16(B + boff + (long)c * 32 * Kstride + k0, bsw + b * TN * 64 + c * 2048);
    };

    f32x4 acc[2][WN];
    #pragma unroll
    for (int i = 0; i < 2; i++)
        #pragma unroll
        for (int j = 0; j < WN; j++)
            acc[i][j] = (f32x4){0.f, 0.f, 0.f, 0.f};

    const int rsw = l16 & 7;   // frag read swizzle: row&7 == l16&7

    stageA(0, 0); stageB(0, 0);
    if (K > 64) { stageA(1, 64); stageB(1, 64); }

    int cur = 0;
    for (int k0 = 0; k0 < K; k0 += 64) {
        if (k0 + 64 < K) { if constexpr (NC == 4) ASM_VMCNT(6); else ASM_VMCNT(4); }
        else ASM_VMCNT(0);
        __builtin_amdgcn_s_barrier();

        const u16* Ar = As + cur * 4096;
        const u16* Br = Bs + cur * TN * 64;
        bf16x8 af[2][2], bfr[WN][2];
        #pragma unroll
        for (int i = 0; i < 2; i++)
            #pragma unroll
            for (int kk = 0; kk < 2; kk++)
                af[i][kk] = *(const bf16x8*)&Ar[(wm * 32 + i * 16 + l16) * 64 + (((kk * 4 + quad) ^ rsw) * 8)];
        #pragma unroll
        for (int j = 0; j < WN; j++)
            #pragma unroll
            for (int kk = 0; kk < 2; kk++)
                bfr[j][kk] = *(const bf16x8*)&Br[(wn * (WN * 16) + j * 16 + l16) * 64 + (((kk * 4 + quad) ^ rsw) * 8)];
        ASM_LGKM0();
        __builtin_amdgcn_s_barrier();
        if (k0 + 128 < K) { stageA(cur, k0 + 128); stageB(cur, k0 + 128); }

        #pragma unroll
        for (int kk = 0; kk < 2; kk++)
            #pragma unroll
            for (int i = 0; i < 2; i++)
                #pragma unroll
                for (int j = 0; j < WN; j++)
                    acc[i][j] = __builtin_amdgcn_mfma_f32_16x16x32_bf16(af[i][kk], bfr[j][kk], acc[i][j], 0, 0, 0);

        cur ^= 1;
    }

    const int rbase = m0 + wm * 32;
    const int cbase = n0 + wn * (WN * 16);
    #pragma unroll
    for (int i = 0; i < 2; i++)
        #pragma unroll
        for (int j = 0; j < WN; j++)
            #pragma unroll
            for (int rg = 0; rg < 4; rg++)
                epi_store<EPI>(acc[i][j][rg], rbase + i * 16 + quad * 4 + rg,
                               cbase + j * 16 + l16, N, (int)blockIdx.z, 0,
                               bias, resid, out0, out1, out2);
}

// ---------------------------------------------------------------------------
// Fused flash attention v3: grid (BHB, 8), 128 threads = 2 waves of 32 q-rows
// (wave tile unchanged from the verified r7 kernel).  384 blocks -> all 256
// CUs busy (was 192 blocks / 1 block/CU).  K staging trimmed to the causal
// range (qblk+1)*64 rows.  T13 defer-max: skip O-rescale when the new tile max
// is within 8 of the running max (P bounded by e^8; f32 accum).
// ---------------------------------------------------------------------------
__global__ __launch_bounds__(128)
void attn_kernel(const u16* __restrict__ qb, const u16* __restrict__ kb,
                 const u16* __restrict__ vtb, u16* __restrict__ ob)
{
    __shared__ __align__(16) u16 Ks[512 * 64];     // 64KB  [kv][d] (first nkv rows used)
    __shared__ __align__(16) u16 Vs[64 * 512];     // 64KB  [d][kv] (V^T)
    __shared__ __align__(16) u16 Ps[2][32 * 64];   // 8KB   per-wave P tile

    const int tid  = threadIdx.x;
    const int wave = tid >> 6;
    const int lane = tid & 63;
    const int quad = lane >> 4;
    const int l16  = lane & 15;

    const int bh   = blockIdx.x;
    const int qblk = blockIdx.y;
    const int qr0  = qblk * 64 + wave * 32;
    const int nkv  = (qblk + 1) * 64;    // causal K range for this block

    // ---- stage K rows [0, nkv): 16 rows per iter (8 per wave)
    for (int cI = 0; cI < (nkv >> 4); ++cI) {
        const int rbase = cI * 16 + wave * 8;
        const int r  = rbase + (lane >> 3);
        const int ch = lane & 7;
        gl2lds16(kb + ((long)bh * SEQ + r) * HD + ((ch ^ (r & 7)) * 8), Ks + rbase * 64);
    }
    // ---- stage V^T: 64 d-rows, 2 per iter (1 per wave)
    #pragma unroll 4
    for (int cI = 0; cI < 32; ++cI) {
        const int d = cI * 2 + wave;
        gl2lds16(vtb + ((long)bh * HD + d) * SEQ + ((lane ^ (d & 7)) * 8), Vs + d * 512);
    }

    bf16x8 af[2][2];
    const long qoff = ((long)bh * SEQ + qr0) * HD;
    #pragma unroll
    for (int i = 0; i < 2; i++)
        #pragma unroll
        for (int kc = 0; kc < 2; kc++)
            af[i][kc] = *(const bf16x8*)&qb[qoff + (long)(i * 16 + l16) * HD + kc * 32 + quad * 8];

    __syncthreads();   // drains vmcnt for the LDS staging (cross-wave rows)

    f32x4 o[2][4];
    float mrun[2][4], lrun[2][4];
    #pragma unroll
    for (int i = 0; i < 2; i++)
        #pragma unroll
        for (int rg = 0; rg < 4; rg++) { mrun[i][rg] = -1e30f; lrun[i][rg] = 0.f; }
    #pragma unroll
    for (int i = 0; i < 2; i++)
        #pragma unroll
        for (int nd = 0; nd < 4; nd++)
            o[i][nd] = (f32x4){0.f, 0.f, 0.f, 0.f};

    u16* const Pw = &Ps[wave][0];
    const int rsw = l16 & 7;
    const int kvend = qr0 + 32;

    for (int kv0 = 0; kv0 < kvend; kv0 += 64) {
        f32x4 s[2][4];
        #pragma unroll
        for (int i = 0; i < 2; i++)
            #pragma unroll
            for (int n = 0; n < 4; n++)
                s[i][n] = (f32x4){0.f, 0.f, 0.f, 0.f};
        bf16x8 bf[4][2];
        #pragma unroll
        for (int n = 0; n < 4; n++)
            #pragma unroll
            for (int kc = 0; kc < 2; kc++)
                bf[n][kc] = *(const bf16x8*)&Ks[(kv0 + n * 16 + l16) * 64 + (((kc * 4 + quad) ^ rsw) * 8)];
        #pragma unroll
        for (int i = 0; i < 2; i++)
            #pragma unroll
            for (int n = 0; n < 4; n++)
                #pragma unroll
                for (int kc = 0; kc < 2; kc++)
                    s[i][n] = __builtin_amdgcn_mfma_f32_16x16x32_bf16(af[i][kc], bf[n][kc], s[i][n], 0, 0, 0);

        #pragma unroll
        for (int i = 0; i < 2; i++) {
            #pragma unroll
            for (int rg = 0; rg < 4; rg++) {
                const int q = qr0 + i * 16 + quad * 4 + rg;
                float v[4];
                #pragma unroll
                for (int n = 0; n < 4; n++) {
                    const int c = kv0 + n * 16 + l16;
                    v[n] = (c <= q) ? s[i][n][rg] * 0.125f : -1e30f;
                }
                float pm = fmaxf(fmaxf(v[0], v[1]), fmaxf(v[2], v[3]));
                #pragma unroll
                for (int off = 1; off < 16; off <<= 1) pm = fmaxf(pm, __shfl_xor(pm, off));
                // T13 defer-max: only rescale when the max moved by > 8.
                if (pm > mrun[i][rg] + 8.f) {
                    const float corr = __expf(mrun[i][rg] - pm);
                    mrun[i][rg] = pm;
                    lrun[i][rg] *= corr;
                    #pragma unroll
                    for (int nd = 0; nd < 4; nd++) o[i][nd][rg] *= corr;
                }
                const float mn = mrun[i][rg];
                float ps = 0.f;
                #pragma unroll
                for (int n = 0; n < 4; n++) { const float e = __expf(v[n] - mn); v[n] = e; ps += e; }
                #pragma unroll
                for (int off = 1; off < 16; off <<= 1) ps += __shfl_xor(ps, off);
                lrun[i][rg] += ps;
                const int qlz = i * 16 + quad * 4 + rg;
                const int sw = qlz & 7;
                #pragma unroll
                for (int n = 0; n < 4; n++)
                    Pw[qlz * 64 + (((n * 2 + (l16 >> 3)) ^ sw) * 8) + (l16 & 7)] = f2bf(v[n]);
            }
        }
        asm volatile("s_waitcnt lgkmcnt(0)" ::: "memory");   // P writes visible wave-wide

        bf16x8 pa[2][2], vb[4][2];
        #pragma unroll
        for (int i = 0; i < 2; i++)
            #pragma unroll
            for (int kc = 0; kc < 2; kc++)
                pa[i][kc] = *(const bf16x8*)&Pw[(i * 16 + l16) * 64 + (((kc * 4 + quad) ^ rsw) * 8)];
        #pragma unroll
        for (int nd = 0; nd < 4; nd++)
            #pragma unroll
            for (int kc = 0; kc < 2; kc++)
                vb[nd][kc] = *(const bf16x8*)&Vs[(nd * 16 + l16) * 512 + ((((kv0 >> 3) + kc * 4 + quad) ^ rsw) * 8)];
        #pragma unroll
        for (int i = 0; i < 2; i++)
            #pragma unroll
            for (int nd = 0; nd < 4; nd++)
                #pragma unroll
                for (int kc = 0; kc < 2; kc++)
                    o[i][nd] = __builtin_amdgcn_mfma_f32_16x16x32_bf16(pa[i][kc], vb[nd][kc], o[i][nd], 0, 0, 0);
    }

    const int b  = bh / NH, hh = bh - b * NH;
    #pragma unroll
    for (int i = 0; i < 2; i++) {
        #pragma unroll
        for (int rg = 0; rg < 4; rg++) {
            const float inv = 1.f / lrun[i][rg];
            const int t = qr0 + i * 16 + quad * 4 + rg;
            u16* orow = ob + ((long)(b * SEQ + t)) * DIM + hh * HD;
            #pragma unroll
            for (int nd = 0; nd < 4; nd++)
                orow[nd * 16 + l16] = f2bf(o[i][nd][rg] * inv);
        }
    }
}

// x = tok_emb[idx] + pos_emb ; fp32 out
__global__ __launch_bounds__(256)
void embed_kernel(const int* __restrict__ tokidx, const float* __restrict__ tok,
                  const float* __restrict__ pos, float* __restrict__ x)
{
    const int i = blockIdx.x * 256 + threadIdx.x;   // float4 index over NTOK*192
    const int row = i / 192;
    const int c4 = i - row * 192;
    const int t = row & (SEQ - 1);
    const int tk = tokidx[row];
    const float4 a = *(const float4*)&tok[(long)tk * DIM + c4 * 4];
    const float4 p = *(const float4*)&pos[(long)t * DIM + c4 * 4];
    *(float4*)&x[(long)row * DIM + c4 * 4] = make_float4(a.x + p.x, a.y + p.y, a.z + p.z, a.w + p.w);
}

// LayerNorm over DIM=768, one wave per row, bf16 out
__global__ __launch_bounds__(256)
void ln_kernel(const float* __restrict__ x, const float* __restrict__ g,
               const float* __restrict__ b, u16* __restrict__ out)
{
    const int row = blockIdx.x * 4 + (threadIdx.x >> 6);
    const int lane = threadIdx.x & 63;
    const float* xr = x + (long)row * DIM;
    float v[12];
    float s = 0.f, s2 = 0.f;
    #pragma unroll
    for (int i = 0; i < 3; i++) {
        const float4 f = *(const float4*)&xr[i * 256 + lane * 4];
        v[i*4+0] = f.x; v[i*4+1] = f.y; v[i*4+2] = f.z; v[i*4+3] = f.w;
        s  += f.x + f.y + f.z + f.w;
        s2 += f.x*f.x + f.y*f.y + f.z*f.z + f.w*f.w;
    }
    for (int o = 32; o; o >>= 1) { s += __shfl_xor(s, o); s2 += __shfl_xor(s2, o); }
    const float m  = s * (1.f / DIM);
    const float var = s2 * (1.f / DIM) - m * m;
    const float rs = rsqrtf(var + 1e-5f);
    u16* orow = out + (long)row * DIM;
    #pragma unroll
    for (int i = 0; i < 3; i++) {
        const int c = i * 256 + lane * 4;
        ushort4 o4 = make_ushort4(
            f2bf((v[i*4+0] - m) * rs * g[c+0] + b[c+0]),
            f2bf((v[i*4+1] - m) * rs * g[c+1] + b[c+1]),
            f2bf((v[i*4+2] - m) * rs * g[c+2] + b[c+2]),
            f2bf((v[i*4+3] - m) * rs * g[c+3] + b[c+3]));
        *(ushort4*)&orow[c] = o4;
    }
}

// fused fp32 -> bf16 bulk convert over TWO buffers (a first, then b)
__global__ __launch_bounds__(256)
void tobf16_2(const float* __restrict__ a, u16* __restrict__ oa,
              const float* __restrict__ b, u16* __restrict__ ob, long na)
{
    long i = ((long)blockIdx.x * 256 + threadIdx.x) * 4;
    const float* src; u16* dst;
    if (i < na) { src = a; dst = oa; }
    else        { i -= na; src = b; dst = ob; }
    const float4 f = *(const float4*)&src[i];
    *(ushort4*)&dst[i] = make_ushort4(f2bf(f.x), f2bf(f.y), f2bf(f.z), f2bf(f.w));
}

// ghost dequant: w[o,k] = bf16(lut[idx[o,k]] * scale[o])
__global__ __launch_bounds__(256)
void dequant_kernel(const int* __restrict__ gidx, const float* __restrict__ scale,
                    const float* __restrict__ lut, u16* __restrict__ w,
                    long total, int Kd)
{
    __shared__ float slut[256];
    slut[threadIdx.x] = lut[threadIdx.x];
    __syncthreads();
    const long i4 = ((long)blockIdx.x * 256 + threadIdx.x) * 4;
    if (i4 >= total) return;
    const int4 g = *(const int4*)&gidx[i4];
    const float sc = scale[(int)(i4 / Kd)];
    *(ushort4*)&w[i4] = make_ushort4(f2bf(slut[g.x] * sc), f2bf(slut[g.y] * sc),
                                     f2bf(slut[g.z] * sc), f2bf(slut[g.w] * sc));
}

// fused ghost dequant for w1 (Kd=DIM) and w2 (Kd=HID): first halfBlocks blocks
// do w1, rest do w2.  Both sides are NL*HID*DIM elements.
__global__ __launch_bounds__(256)
void dequant2_kernel(const int* __restrict__ g1, const float* __restrict__ s1,
                     const int* __restrict__ g2, const float* __restrict__ s2,
                     const float* __restrict__ lut,
                     u16* __restrict__ w1, u16* __restrict__ w2, long halfBlocks)
{
    __shared__ float slut[256];
    slut[threadIdx.x] = lut[threadIdx.x];
    __syncthreads();
    const long bid = blockIdx.x;
    const int* g; const float* s; u16* w; int Kd; long i4;
    if (bid < halfBlocks) { g = g1; s = s1; w = w1; Kd = DIM; i4 = (bid * 256 + threadIdx.x) * 4; }
    else                  { g = g2; s = s2; w = w2; Kd = HID; i4 = ((bid - halfBlocks) * 256 + threadIdx.x) * 4; }
    const int4 q = *(const int4*)&g[i4];
    const float sc = s[(long)(i4 / Kd)];
    *(ushort4*)&w[i4] = make_ushort4(f2bf(slut[q.x] * sc), f2bf(slut[q.y] * sc),
                                     f2bf(slut[q.z] * sc), f2bf(slut[q.w] * sc));
}

extern "C" void kernel_launch(void* const* d_in, const int* in_sizes, int n_in,
                              void* d_out, int out_size, void* d_ws, size_t ws_size,
                              hipStream_t stream)
{
    const float* lut        = (const float*)d_in[0];
    const float* tok_emb    = (const float*)d_in[1];
    const float* pos_emb    = (const float*)d_in[2];
    const float* ln1_g      = (const float*)d_in[3];
    const float* ln1_b      = (const float*)d_in[4];
    const float* in_w       = (const float*)d_in[5];
    const float* in_b       = (const float*)d_in[6];
    const float* out_w      = (const float*)d_in[7];
    const float* out_b      = (const float*)d_in[8];
    const float* ln2_g      = (const float*)d_in[9];
    const float* ln2_b      = (const float*)d_in[10];
    const float* mlp1_scale = (const float*)d_in[11];
    const float* mlp2_scale = (const float*)d_in[12];
    const float* lnf_g      = (const float*)d_in[13];
    const float* lnf_b      = (const float*)d_in[14];
    const float* head_scale = (const float*)d_in[15];
    const int*   mlp1_idx   = (const int*)d_in[16];
    const int*   mlp2_idx   = (const int*)d_in[17];
    const int*   head_idx   = (const int*)d_in[18];
    const int*   tokids     = (const int*)d_in[19];

    char* p = (char*)d_ws;
    auto alloc = [&](size_t bytes) { char* r = p; p += (bytes + 255) & ~(size_t)255; return r; };
    float* x    = (float*)alloc((size_t)NTOK * DIM * 4);
    u16*  h     = (u16*) alloc((size_t)NTOK * DIM * 2);
    u16*  h2    = (u16*) alloc((size_t)NTOK * HID * 2);
    u16*  qb    = (u16*) alloc((size_t)BHB * SEQ * HD * 2);
    u16*  kb    = (u16*) alloc((size_t)BHB * SEQ * HD * 2);
    u16*  vtb   = (u16*) alloc((size_t)BHB * SEQ * HD * 2);
    u16*  ob    = (u16*) alloc((size_t)NTOK * DIM * 2);
    u16*  inw16 = (u16*) alloc((size_t)NL * 3 * DIM * DIM * 2);
    u16*  outw16= (u16*) alloc((size_t)NL * DIM * DIM * 2);
    u16*  hw    = (u16*) alloc((size_t)VOCAB * DIM * 2);

    // dequant hoist: all 13 layers of mlp1/mlp2 weights in the prologue, if
    // the workspace is big enough; else per-layer fallback.
    const size_t layerW = (size_t)HID * DIM * 2;          // 4.7 MB
    const size_t used   = (size_t)(p - (char*)d_ws);
    const bool hoist    = ws_size >= used + 2 * NL * layerW + 1024;
    u16* w1 = (u16*)alloc(hoist ? NL * layerW : layerW);
    u16* w2 = (u16*)alloc(hoist ? NL * layerW : layerW);

    embed_kernel<<<NTOK * 192 / 256, 256, 0, stream>>>(tokids, tok_emb, pos_emb, x);
    {
        const long na = (long)NL * 3 * DIM * DIM;
        const long nb = (long)NL * DIM * DIM;
        tobf16_2<<<(int)((na + nb) / 1024), 256, 0, stream>>>(in_w, inw16, out_w, outw16, na);
    }
    {
        const long total = (long)VOCAB * DIM;
        const int blocks = (int)((total / 4 + 255) / 256);
        dequant_kernel<<<blocks, 256, 0, stream>>>(head_idx, head_scale, lut, hw, total, DIM);
    }
    if (hoist) {
        const long t1 = (long)NL * HID * DIM;
        const long halfBlocks = t1 / 1024;
        dequant2_kernel<<<(int)(2 * halfBlocks), 256, 0, stream>>>(
            mlp1_idx, mlp1_scale, mlp2_idx, mlp2_scale, lut, w1, w2, halfBlocks);
    }

    for (int l = 0; l < NL; l++) {
        u16* w1l = hoist ? w1 + (size_t)l * HID * DIM : w1;
        u16* w2l = hoist ? w2 + (size_t)l * HID * DIM : w2;

        ln_kernel<<<NTOK / 4, 256, 0, stream>>>(x, ln1_g + l * DIM, ln1_b + l * DIM, h);
        gemm64<4, 1><<<dim3(NTOK / 64, 3 * DIM / 128), 256, 0, stream>>>(
            h, inw16 + (long)l * 3 * DIM * DIM, in_b + l * 3 * DIM, nullptr,
            qb, kb, vtb, NTOK, 3 * DIM, DIM, DIM);
        attn_kernel<<<dim3(BHB, 8), 128, 0, stream>>>(qb, kb, vtb, ob);
        // outproj: split-K=2, partials atomic-added into x (bias at z==0).
        gemm64<2, 5><<<dim3(NTOK / 64, DIM / 64, 2), 256, 0, stream>>>(
            ob, outw16 + (long)l * DIM * DIM, out_b + l * DIM, nullptr,
            x, nullptr, nullptr, NTOK, DIM, DIM / 2, DIM);
        ln_kernel<<<NTOK / 4, 256, 0, stream>>>(x, ln2_g + l * DIM, ln2_b + l * DIM, h);
        if (!hoist)
            dequant_kernel<<<HID * DIM / 1024, 256, 0, stream>>>(
                mlp1_idx + (long)l * HID * DIM, mlp1_scale + l * HID, lut, w1l, (long)HID * DIM, DIM);
        gemm64<4, 4><<<dim3(NTOK / 64, HID / 128), 256, 0, stream>>>(
            h, w1l, nullptr, nullptr, h2, nullptr, nullptr, NTOK, HID, DIM, DIM);
        if (!hoist)
            dequant_kernel<<<DIM * HID / 1024, 256, 0, stream>>>(
                mlp2_idx + (long)l * DIM * HID, mlp2_scale + l * DIM, lut, w2l, (long)DIM * HID, HID);
        // mlp2: split-K=4 (K=3072 -> 4x768), partials atomic-added into x.
        gemm64<2, 5><<<dim3(NTOK / 64, DIM / 64, 4), 256, 0, stream>>>(
            h2, w2l, nullptr, nullptr, x, nullptr, nullptr, NTOK, DIM, HID / 4, HID);
    }

    ln_kernel<<<NTOK / 4, 256, 0, stream>>>(x, lnf_g, lnf_b, h);
    gemm_bt<4, 0><<<dim3(NTOK / 128, (VOCAB + 127) / 128, 1), 256, 0, stream>>>(
        h, hw, nullptr, nullptr, d_out, nullptr, nullptr, NTOK, VOCAB, DIM, 0, 0, 0);
}

// Round 11
// 2642.988 us; speedup vs baseline: 1.1014x; 1.1014x over previous
//
#include <hip/hip_runtime.h>
#include <stdint.h>

#define DIM 768
#define NL 13
#define NH 12
#define VOCAB 50257
#define SEQ 512
#define BATCH 4
#define HID 3072
#define HD 64
#define NTOK (BATCH*SEQ)   // 2048
#define BHB (BATCH*NH)     // 48 batched heads

typedef unsigned short u16;
typedef __attribute__((ext_vector_type(8))) __bf16 bf16x8;
typedef __attribute__((ext_vector_type(4))) float f32x4;

#define ASM_VMCNT(N) asm volatile("s_waitcnt vmcnt(" #N ")" ::: "memory")
#define ASM_LGKM0()  asm volatile("s_waitcnt lgkmcnt(0)" ::: "memory")

__device__ __forceinline__ u16 f2bf(float f) {
    union { float f; uint32_t u; } v; v.f = f;
    uint32_t u = v.u;
    return (u16)((u + 0x7FFFu + ((u >> 16) & 1u)) >> 16);   // RNE
}

__device__ __forceinline__ void gl2lds16(const void* g, void* l) {
    // async global->LDS, 16B/lane; LDS dest = wave-uniform base + lane*16
    __builtin_amdgcn_global_load_lds((const __attribute__((address_space(1))) void*)g,
                                     (__attribute__((address_space(3))) void*)l,
                                     16, 0, 0);
}

__device__ __forceinline__ float gelu_tanh(float x) {
    // tanh(y) = 1 - 2/(exp(2y)+1) via HW v_exp_f32 (no tanh instruction on gfx950)
    const float y = 0.7978845608028654f * (x + 0.044715f * x * x * x);
    const float t = 1.0f - 2.0f / (__expf(2.0f * y) + 1.0f);
    return 0.5f * x * (1.0f + t);
}

__device__ __forceinline__ void xcd_remap(int& bx, int& by) {
    const int gx = gridDim.x;
    const int nwg = gx * gridDim.y;
    const int orig = by * gx + bx;
    const int xcd = orig & 7;
    const int q = nwg >> 3, r = nwg & 7;
    const int wg = (xcd < r ? xcd * (q + 1) : r * (q + 1) + (xcd - r) * q) + (orig >> 3);
    bx = wg % gx; by = wg / gx;
}

// ---------------------------------------------------------------------------
// Shared epilogue.
// EPI: 0 plain f32 (col-bound checked), 1 qkv scatter, 3 f32 + bias + residual,
//      4 gelu -> bf16, 5 f32 atomic accumulate (split-K; resid pre-resident in
//      out0; bias added exactly once by the z==0 block)
// ---------------------------------------------------------------------------
template<int EPI>
__device__ __forceinline__ void epi_store(float v, int r, int c, int N, int z, long sC,
                                          const float* bias, const float* resid,
                                          void* out0, void* out1, void* out2)
{
    if constexpr (EPI == 0) {
        if (c < N) ((float*)out0)[(long)z * sC + (long)r * N + c] = v;
    } else if constexpr (EPI == 1) {
        v += bias[c];
        const int part = c / DIM;
        const int cc = c - part * DIM;
        const int hh = cc >> 6, d = cc & 63;
        const int b = r >> 9, t = r & 511;
        const int bh = b * NH + hh;
        if (part == 0)      ((u16*)out0)[((long)bh * SEQ + t) * HD + d] = f2bf(v);
        else if (part == 1) ((u16*)out1)[((long)bh * SEQ + t) * HD + d] = f2bf(v);
        else                ((u16*)out2)[((long)bh * HD + d) * SEQ + t] = f2bf(v);
    } else if constexpr (EPI == 3) {
        if (bias) v += bias[c];
        v += resid[(long)r * N + c];
        ((float*)out0)[(long)r * N + c] = v;
    } else if constexpr (EPI == 5) {
        if (bias && z == 0) v += bias[c];
        atomicAdd(&((float*)out0)[(long)r * N + c], v);
    } else {
        ((u16*)out0)[(long)r * N + c] = f2bf(gelu_tanh(v));
    }
}

// ---------------------------------------------------------------------------
// Head GEMM: 128 x (WN*32) tile, BK=32, depth-2 counted-vmcnt pipeline.
// WN=4 kept: m112 measured 128^2 (912 TF) > 128x256 (823) at this structure.
// ---------------------------------------------------------------------------
template<int WN, int EPI>
__global__ __launch_bounds__(256)
void gemm_bt(const u16* __restrict__ A, const u16* __restrict__ B,
             const float* __restrict__ bias, const float* __restrict__ resid,
             void* __restrict__ out0, void* __restrict__ out1, void* __restrict__ out2,
             int M, int N, int K, long sA, long sB, long sC)
{
    constexpr int TN = WN * 32;
    constexpr int NBG = TN / 64;                   // B staging groups of 64 rows
    __shared__ __align__(16) u16 As[2 * 128 * 32];
    __shared__ __align__(16) u16 Bs[2 * TN * 32];

    const int tid  = threadIdx.x;
    const int wave = tid >> 6;
    const int lane = tid & 63;
    const int quad = lane >> 4;
    const int l16  = lane & 15;
    const int wm   = wave >> 1;
    const int wn   = wave & 1;

    int bx = blockIdx.x, by = blockIdx.y;
    xcd_remap(bx, by);

    const int m0 = bx * 128;
    const int n0 = by * TN;
    const int z  = blockIdx.z;

    const u16* Ab = A + (long)z * sA;
    const u16* Bb = B + (long)z * sB;

    const int srow = tid >> 2;          // 0..63
    const int scol = ((tid & 3) ^ ((srow >> 1) & 3)) * 8;   // pre-swizzled k-chunk

    const long aoff0 = (long)(m0 + srow) * K + scol;
    const long aoff1 = (long)(m0 + 64 + srow) * K + scol;
    long boff[NBG];
    #pragma unroll
    for (int g = 0; g < NBG; g++) {
        int br = n0 + g * 64 + srow; if (br > N - 1) br = N - 1;
        boff[g] = (long)br * K + scol;
    }

    auto stage = [&](int b, int k0) {
        gl2lds16(Ab + aoff0 + k0, As + b * 4096 + wave * 512);
        gl2lds16(Ab + aoff1 + k0, As + b * 4096 + 2048 + wave * 512);
        #pragma unroll
        for (int g = 0; g < NBG; g++)
            gl2lds16(Bb + boff[g] + k0, Bs + b * (TN * 32) + g * 2048 + wave * 512);
    };

    f32x4 acc[4][WN];
    #pragma unroll
    for (int i = 0; i < 4; i++)
        #pragma unroll
        for (int j = 0; j < WN; j++)
            acc[i][j] = (f32x4){0.f, 0.f, 0.f, 0.f};

    const int sq8 = (quad ^ ((l16 >> 1) & 3)) * 8;
    const int arow = (wm * 64 + l16) * 32 + sq8;
    const int brow = (wn * (WN * 16) + l16) * 32 + sq8;

    stage(0, 0);
    if (K > 32) stage(1, 32);

    int cur = 0;
    for (int k0 = 0; k0 < K; k0 += 32) {
        // land step k0's loads; step k0+32's (4 newest) may stay in flight
        if (k0 + 32 < K) ASM_VMCNT(4); else ASM_VMCNT(0);
        __builtin_amdgcn_s_barrier();

        const u16* Ar = As + cur * 4096;
        const u16* Br = Bs + cur * (TN * 32);
        bf16x8 af[4], bfr[WN];
        #pragma unroll
        for (int i = 0; i < 4; i++)
            af[i] = *(const bf16x8*)&Ar[arow + i * 512];
        #pragma unroll
        for (int j = 0; j < WN; j++)
            bfr[j] = *(const bf16x8*)&Br[brow + j * 512];
        ASM_LGKM0();                       // own reads done before signalling
        __builtin_amdgcn_s_barrier();      // all waves done reading buf cur
        if (k0 + 64 < K) stage(cur, k0 + 64);   // restage 2 steps ahead

        #pragma unroll
        for (int i = 0; i < 4; i++)
            #pragma unroll
            for (int j = 0; j < WN; j++)
                acc[i][j] = __builtin_amdgcn_mfma_f32_16x16x32_bf16(af[i], bfr[j], acc[i][j], 0, 0, 0);

        cur ^= 1;
    }

    const int rbase = m0 + wm * 64;
    const int cbase = n0 + wn * (WN * 16);
    #pragma unroll
    for (int i = 0; i < 4; i++)
        #pragma unroll
        for (int j = 0; j < WN; j++)
            #pragma unroll
            for (int rg = 0; rg < 4; rg++)
                epi_store<EPI>(acc[i][j][rg], rbase + i * 16 + quad * 4 + rg,
                               cbase + j * 16 + l16, N, z, sC, bias, resid, out0, out1, out2);
}

// ---------------------------------------------------------------------------
// Layer GEMM: 64 x (WN*32) tile, BK=64, depth-2 counted-vmcnt pipeline.
// Split-K via blockIdx.z (EPI=5 atomic accumulate, bias at z==0).
// Requires M%64==0, N%TN==0, K%64==0.
// ---------------------------------------------------------------------------
template<int WN, int EPI>
__global__ __launch_bounds__(256)
void gemm64(const u16* __restrict__ A, const u16* __restrict__ B,
            const float* __restrict__ bias, const float* __restrict__ resid,
            void* __restrict__ out0, void* __restrict__ out1, void* __restrict__ out2,
            int M, int N, int K, int Kstride)
{
    constexpr int TN = WN * 32;
    constexpr int NC = TN / 32;                    // B staging sub-blocks of 32 rows
    __shared__ __align__(16) u16 As[2 * 64 * 64];  // 16 KB
    __shared__ __align__(16) u16 Bs[2 * TN * 64];  // 32 or 16 KB

    const int tid  = threadIdx.x;
    const int wave = tid >> 6;
    const int lane = tid & 63;
    const int quad = lane >> 4;
    const int l16  = lane & 15;
    const int wm   = wave >> 1;
    const int wn   = wave & 1;

    int bx = blockIdx.x, by = blockIdx.y;
    xcd_remap(bx, by);
    const int m0 = bx * 64;
    const int n0 = by * TN;
    const int koff = blockIdx.z * K;

    // staging geometry: row = c*32 + (tid>>3), chunk = tid&7 (8 elems / 16 B)
    const int srow = tid >> 3;                       // 0..31
    const int sch  = ((tid & 7) ^ (srow & 7)) * 8;   // swizzled chunk (elems)
    u16* const asw = As + wave * 512;                // wave*8 rows * 64
    u16* const bsw = Bs + wave * 512;

    const long aoff = (long)(m0 + srow) * Kstride + koff + sch;
    const long boff = (long)(n0 + srow) * Kstride + koff + sch;

    auto stageA = [&](int b, int k0) {
        #pragma unroll
        for (int c = 0; c < 2; c++)
            gl2lds16(A + aoff + (long)c * 32 * Kstride + k0, asw + b * 4096 + c * 2048);
    };
    auto stageB = [&](int b, int k0) {
        #pragma unroll
        for (int c = 0; c < NC; c++)
            gl2lds16(B + boff + (long)c * 32 * Kstride + k0, bsw + b * TN * 64 + c * 2048);
    };

    f32x4 acc[2][WN];
    #pragma unroll
    for (int i = 0; i < 2; i++)
        #pragma unroll
        for (int j = 0; j < WN; j++)
            acc[i][j] = (f32x4){0.f, 0.f, 0.f, 0.f};

    const int rsw = l16 & 7;   // frag read swizzle: row&7 == l16&7

    stageA(0, 0); stageB(0, 0);
    if (K > 64) { stageA(1, 64); stageB(1, 64); }

    int cur = 0;
    for (int k0 = 0; k0 < K; k0 += 64) {
        if (k0 + 64 < K) { if constexpr (NC == 4) ASM_VMCNT(6); else ASM_VMCNT(4); }
        else ASM_VMCNT(0);
        __builtin_amdgcn_s_barrier();

        const u16* Ar = As + cur * 4096;
        const u16* Br = Bs + cur * TN * 64;
        bf16x8 af[2][2], bfr[WN][2];
        #pragma unroll
        for (int i = 0; i < 2; i++)
            #pragma unroll
            for (int kk = 0; kk < 2; kk++)
                af[i][kk] = *(const bf16x8*)&Ar[(wm * 32 + i * 16 + l16) * 64 + (((kk * 4 + quad) ^ rsw) * 8)];
        #pragma unroll
        for (int j = 0; j < WN; j++)
            #pragma unroll
            for (int kk = 0; kk < 2; kk++)
                bfr[j][kk] = *(const bf16x8*)&Br[(wn * (WN * 16) + j * 16 + l16) * 64 + (((kk * 4 + quad) ^ rsw) * 8)];
        ASM_LGKM0();
        __builtin_amdgcn_s_barrier();
        if (k0 + 128 < K) { stageA(cur, k0 + 128); stageB(cur, k0 + 128); }

        #pragma unroll
        for (int kk = 0; kk < 2; kk++)
            #pragma unroll
            for (int i = 0; i < 2; i++)
                #pragma unroll
                for (int j = 0; j < WN; j++)
                    acc[i][j] = __builtin_amdgcn_mfma_f32_16x16x32_bf16(af[i][kk], bfr[j][kk], acc[i][j], 0, 0, 0);

        cur ^= 1;
    }

    const int rbase = m0 + wm * 32;
    const int cbase = n0 + wn * (WN * 16);
    #pragma unroll
    for (int i = 0; i < 2; i++)
        #pragma unroll
        for (int j = 0; j < WN; j++)
            #pragma unroll
            for (int rg = 0; rg < 4; rg++)
                epi_store<EPI>(acc[i][j][rg], rbase + i * 16 + quad * 4 + rg,
                               cbase + j * 16 + l16, N, (int)blockIdx.z, 0,
                               bias, resid, out0, out1, out2);
}

// ---------------------------------------------------------------------------
// Fused flash attention (round-9 geometry: 256 threads, grid (BHB,4), 4 waves
// of 32 q-rows; K/V staged to LDS with XOR-chunk swizzle).  Two verified adds:
// causal K-stage trim (qblk stages (qblk+1)*128 rows, avg -37% staging) and
// T13 defer-max (skip O-rescale when tile max moved <= 8; refcheck'd r10).
// ---------------------------------------------------------------------------
__global__ __launch_bounds__(256)
void attn_kernel(const u16* __restrict__ qb, const u16* __restrict__ kb,
                 const u16* __restrict__ vtb, u16* __restrict__ ob)
{
    __shared__ __align__(16) u16 Ks[512 * 64];     // 64KB  [kv][d] (first nkv rows used)
    __shared__ __align__(16) u16 Vs[64 * 512];     // 64KB  [d][kv] (V^T)
    __shared__ __align__(16) u16 Ps[4][32 * 64];   // 16KB  per-wave P tile

    const int tid  = threadIdx.x;
    const int wave = tid >> 6;
    const int lane = tid & 63;
    const int quad = lane >> 4;
    const int l16  = lane & 15;

    const int bh   = blockIdx.x;
    const int qblk = blockIdx.y;
    const int qr0  = qblk * 128 + wave * 32;
    const int nIter = (qblk + 1) * 4;    // stage (qblk+1)*128 K rows (causal)

    #pragma unroll 4
    for (int cI = 0; cI < nIter; ++cI) {
        const int rbase = cI * 32 + wave * 8;
        const int r  = rbase + (lane >> 3);
        const int ch = lane & 7;
        gl2lds16(kb + ((long)bh * SEQ + r) * HD + ((ch ^ (r & 7)) * 8), Ks + rbase * 64);
    }
    #pragma unroll 4
    for (int cI = 0; cI < 16; ++cI) {
        const int d = cI * 4 + wave;
        gl2lds16(vtb + ((long)bh * HD + d) * SEQ + ((lane ^ (d & 7)) * 8), Vs + d * 512);
    }

    bf16x8 af[2][2];
    const long qoff = ((long)bh * SEQ + qr0) * HD;
    #pragma unroll
    for (int i = 0; i < 2; i++)
        #pragma unroll
        for (int kc = 0; kc < 2; kc++)
            af[i][kc] = *(const bf16x8*)&qb[qoff + (long)(i * 16 + l16) * HD + kc * 32 + quad * 8];

    __syncthreads();   // drains vmcnt for the LDS staging

    f32x4 o[2][4];
    float mrun[2][4], lrun[2][4];
    #pragma unroll
    for (int i = 0; i < 2; i++)
        #pragma unroll
        for (int rg = 0; rg < 4; rg++) { mrun[i][rg] = -1e30f; lrun[i][rg] = 0.f; }
    #pragma unroll
    for (int i = 0; i < 2; i++)
        #pragma unroll
        for (int nd = 0; nd < 4; nd++)
            o[i][nd] = (f32x4){0.f, 0.f, 0.f, 0.f};

    u16* const Pw = &Ps[wave][0];
    const int rsw = l16 & 7;
    const int kvend = qr0 + 32;

    for (int kv0 = 0; kv0 < kvend; kv0 += 64) {
        f32x4 s[2][4];
        #pragma unroll
        for (int i = 0; i < 2; i++)
            #pragma unroll
            for (int n = 0; n < 4; n++)
                s[i][n] = (f32x4){0.f, 0.f, 0.f, 0.f};
        bf16x8 bf[4][2];
        #pragma unroll
        for (int n = 0; n < 4; n++)
            #pragma unroll
            for (int kc = 0; kc < 2; kc++)
                bf[n][kc] = *(const bf16x8*)&Ks[(kv0 + n * 16 + l16) * 64 + (((kc * 4 + quad) ^ rsw) * 8)];
        #pragma unroll
        for (int i = 0; i < 2; i++)
            #pragma unroll
            for (int n = 0; n < 4; n++)
                #pragma unroll
                for (int kc = 0; kc < 2; kc++)
                    s[i][n] = __builtin_amdgcn_mfma_f32_16x16x32_bf16(af[i][kc], bf[n][kc], s[i][n], 0, 0, 0);

        #pragma unroll
        for (int i = 0; i < 2; i++) {
            #pragma unroll
            for (int rg = 0; rg < 4; rg++) {
                const int q = qr0 + i * 16 + quad * 4 + rg;
                float v[4];
                #pragma unroll
                for (int n = 0; n < 4; n++) {
                    const int c = kv0 + n * 16 + l16;
                    v[n] = (c <= q) ? s[i][n][rg] * 0.125f : -1e30f;
                }
                float pm = fmaxf(fmaxf(v[0], v[1]), fmaxf(v[2], v[3]));
                #pragma unroll
                for (int off = 1; off < 16; off <<= 1) pm = fmaxf(pm, __shfl_xor(pm, off));
                // T13 defer-max: only rescale when the max moved by > 8.
                if (pm > mrun[i][rg] + 8.f) {
                    const float corr = __expf(mrun[i][rg] - pm);
                    mrun[i][rg] = pm;
                    lrun[i][rg] *= corr;
                    #pragma unroll
                    for (int nd = 0; nd < 4; nd++) o[i][nd][rg] *= corr;
                }
                const float mn = mrun[i][rg];
                float ps = 0.f;
                #pragma unroll
                for (int n = 0; n < 4; n++) { const float e = __expf(v[n] - mn); v[n] = e; ps += e; }
                #pragma unroll
                for (int off = 1; off < 16; off <<= 1) ps += __shfl_xor(ps, off);
                lrun[i][rg] += ps;
                const int qlz = i * 16 + quad * 4 + rg;
                const int sw = qlz & 7;
                #pragma unroll
                for (int n = 0; n < 4; n++)
                    Pw[qlz * 64 + (((n * 2 + (l16 >> 3)) ^ sw) * 8) + (l16 & 7)] = f2bf(v[n]);
            }
        }
        asm volatile("s_waitcnt lgkmcnt(0)" ::: "memory");   // P writes visible wave-wide

        bf16x8 pa[2][2], vb[4][2];
        #pragma unroll
        for (int i = 0; i < 2; i++)
            #pragma unroll
            for (int kc = 0; kc < 2; kc++)
                pa[i][kc] = *(const bf16x8*)&Pw[(i * 16 + l16) * 64 + (((kc * 4 + quad) ^ rsw) * 8)];
        #pragma unroll
        for (int nd = 0; nd < 4; nd++)
            #pragma unroll
            for (int kc = 0; kc < 2; kc++)
                vb[nd][kc] = *(const bf16x8*)&Vs[(nd * 16 + l16) * 512 + ((((kv0 >> 3) + kc * 4 + quad) ^ rsw) * 8)];
        #pragma unroll
        for (int i = 0; i < 2; i++)
            #pragma unroll
            for (int nd = 0; nd < 4; nd++)
                #pragma unroll
                for (int kc = 0; kc < 2; kc++)
                    o[i][nd] = __builtin_amdgcn_mfma_f32_16x16x32_bf16(pa[i][kc], vb[nd][kc], o[i][nd], 0, 0, 0);
    }

    const int b  = bh / NH, hh = bh - b * NH;
    #pragma unroll
    for (int i = 0; i < 2; i++) {
        #pragma unroll
        for (int rg = 0; rg < 4; rg++) {
            const float inv = 1.f / lrun[i][rg];
            const int t = qr0 + i * 16 + quad * 4 + rg;
            u16* orow = ob + ((long)(b * SEQ + t)) * DIM + hh * HD;
            #pragma unroll
            for (int nd = 0; nd < 4; nd++)
                orow[nd * 16 + l16] = f2bf(o[i][nd][rg] * inv);
        }
    }
}

// x = tok_emb[idx] + pos_emb ; fp32 out
__global__ __launch_bounds__(256)
void embed_kernel(const int* __restrict__ tokidx, const float* __restrict__ tok,
                  const float* __restrict__ pos, float* __restrict__ x)
{
    const int i = blockIdx.x * 256 + threadIdx.x;   // float4 index over NTOK*192
    const int row = i / 192;
    const int c4 = i - row * 192;
    const int t = row & (SEQ - 1);
    const int tk = tokidx[row];
    const float4 a = *(const float4*)&tok[(long)tk * DIM + c4 * 4];
    const float4 p = *(const float4*)&pos[(long)t * DIM + c4 * 4];
    *(float4*)&x[(long)row * DIM + c4 * 4] = make_float4(a.x + p.x, a.y + p.y, a.z + p.z, a.w + p.w);
}

// LayerNorm over DIM=768, one wave per row, bf16 out
__global__ __launch_bounds__(256)
void ln_kernel(const float* __restrict__ x, const float* __restrict__ g,
               const float* __restrict__ b, u16* __restrict__ out)
{
    const int row = blockIdx.x * 4 + (threadIdx.x >> 6);
    const int lane = threadIdx.x & 63;
    const float* xr = x + (long)row * DIM;
    float v[12];
    float s = 0.f, s2 = 0.f;
    #pragma unroll
    for (int i = 0; i < 3; i++) {
        const float4 f = *(const float4*)&xr[i * 256 + lane * 4];
        v[i*4+0] = f.x; v[i*4+1] = f.y; v[i*4+2] = f.z; v[i*4+3] = f.w;
        s  += f.x + f.y + f.z + f.w;
        s2 += f.x*f.x + f.y*f.y + f.z*f.z + f.w*f.w;
    }
    for (int o = 32; o; o >>= 1) { s += __shfl_xor(s, o); s2 += __shfl_xor(s2, o); }
    const float m  = s * (1.f / DIM);
    const float var = s2 * (1.f / DIM) - m * m;
    const float rs = rsqrtf(var + 1e-5f);
    u16* orow = out + (long)row * DIM;
    #pragma unroll
    for (int i = 0; i < 3; i++) {
        const int c = i * 256 + lane * 4;
        ushort4 o4 = make_ushort4(
            f2bf((v[i*4+0] - m) * rs * g[c+0] + b[c+0]),
            f2bf((v[i*4+1] - m) * rs * g[c+1] + b[c+1]),
            f2bf((v[i*4+2] - m) * rs * g[c+2] + b[c+2]),
            f2bf((v[i*4+3] - m) * rs * g[c+3] + b[c+3]));
        *(ushort4*)&orow[c] = o4;
    }
}

// fused fp32 -> bf16 bulk convert over TWO buffers (a first, then b)
__global__ __launch_bounds__(256)
void tobf16_2(const float* __restrict__ a, u16* __restrict__ oa,
              const float* __restrict__ b, u16* __restrict__ ob, long na)
{
    long i = ((long)blockIdx.x * 256 + threadIdx.x) * 4;
    const float* src; u16* dst;
    if (i < na) { src = a; dst = oa; }
    else        { i -= na; src = b; dst = ob; }
    const float4 f = *(const float4*)&src[i];
    *(ushort4*)&dst[i] = make_ushort4(f2bf(f.x), f2bf(f.y), f2bf(f.z), f2bf(f.w));
}

// ghost dequant: w[o,k] = bf16(lut[idx[o,k]] * scale[o])
__global__ __launch_bounds__(256)
void dequant_kernel(const int* __restrict__ gidx, const float* __restrict__ scale,
                    const float* __restrict__ lut, u16* __restrict__ w,
                    long total, int Kd)
{
    __shared__ float slut[256];
    slut[threadIdx.x] = lut[threadIdx.x];
    __syncthreads();
    const long i4 = ((long)blockIdx.x * 256 + threadIdx.x) * 4;
    if (i4 >= total) return;
    const int4 g = *(const int4*)&gidx[i4];
    const float sc = scale[(int)(i4 / Kd)];
    *(ushort4*)&w[i4] = make_ushort4(f2bf(slut[g.x] * sc), f2bf(slut[g.y] * sc),
                                     f2bf(slut[g.z] * sc), f2bf(slut[g.w] * sc));
}

// fused ghost dequant for w1 (Kd=DIM) and w2 (Kd=HID): first halfBlocks blocks
// do w1, rest do w2.  Both sides are NL*HID*DIM elements.
__global__ __launch_bounds__(256)
void dequant2_kernel(const int* __restrict__ g1, const float* __restrict__ s1,
                     const int* __restrict__ g2, const float* __restrict__ s2,
                     const float* __restrict__ lut,
                     u16* __restrict__ w1, u16* __restrict__ w2, long halfBlocks)
{
    __shared__ float slut[256];
    slut[threadIdx.x] = lut[threadIdx.x];
    __syncthreads();
    const long bid = blockIdx.x;
    const int* g; const float* s; u16* w; int Kd; long i4;
    if (bid < halfBlocks) { g = g1; s = s1; w = w1; Kd = DIM; i4 = (bid * 256 + threadIdx.x) * 4; }
    else                  { g = g2; s = s2; w = w2; Kd = HID; i4 = ((bid - halfBlocks) * 256 + threadIdx.x) * 4; }
    const int4 q = *(const int4*)&g[i4];
    const float sc = s[(long)(i4 / Kd)];
    *(ushort4*)&w[i4] = make_ushort4(f2bf(slut[q.x] * sc), f2bf(slut[q.y] * sc),
                                     f2bf(slut[q.z] * sc), f2bf(slut[q.w] * sc));
}

extern "C" void kernel_launch(void* const* d_in, const int* in_sizes, int n_in,
                              void* d_out, int out_size, void* d_ws, size_t ws_size,
                              hipStream_t stream)
{
    const float* lut        = (const float*)d_in[0];
    const float* tok_emb    = (const float*)d_in[1];
    const float* pos_emb    = (const float*)d_in[2];
    const float* ln1_g      = (const float*)d_in[3];
    const float* ln1_b      = (const float*)d_in[4];
    const float* in_w       = (const float*)d_in[5];
    const float* in_b       = (const float*)d_in[6];
    const float* out_w      = (const float*)d_in[7];
    const float* out_b      = (const float*)d_in[8];
    const float* ln2_g      = (const float*)d_in[9];
    const float* ln2_b      = (const float*)d_in[10];
    const float* mlp1_scale = (const float*)d_in[11];
    const float* mlp2_scale = (const float*)d_in[12];
    const float* lnf_g      = (const float*)d_in[13];
    const float* lnf_b      = (const float*)d_in[14];
    const float* head_scale = (const float*)d_in[15];
    const int*   mlp1_idx   = (const int*)d_in[16];
    const int*   mlp2_idx   = (const int*)d_in[17];
    const int*   head_idx   = (const int*)d_in[18];
    const int*   tokids     = (const int*)d_in[19];

    char* p = (char*)d_ws;
    auto alloc = [&](size_t bytes) { char* r = p; p += (bytes + 255) & ~(size_t)255; return r; };
    float* x    = (float*)alloc((size_t)NTOK * DIM * 4);
    u16*  h     = (u16*) alloc((size_t)NTOK * DIM * 2);
    u16*  h2    = (u16*) alloc((size_t)NTOK * HID * 2);
    u16*  qb    = (u16*) alloc((size_t)BHB * SEQ * HD * 2);
    u16*  kb    = (u16*) alloc((size_t)BHB * SEQ * HD * 2);
    u16*  vtb   = (u16*) alloc((size_t)BHB * SEQ * HD * 2);
    u16*  ob    = (u16*) alloc((size_t)NTOK * DIM * 2);
    u16*  inw16 = (u16*) alloc((size_t)NL * 3 * DIM * DIM * 2);
    u16*  outw16= (u16*) alloc((size_t)NL * DIM * DIM * 2);
    u16*  hw    = (u16*) alloc((size_t)VOCAB * DIM * 2);

    // dequant hoist: all 13 layers of mlp1/mlp2 weights in the prologue, if
    // the workspace is big enough; else per-layer fallback.
    const size_t layerW = (size_t)HID * DIM * 2;          // 4.7 MB
    const size_t used   = (size_t)(p - (char*)d_ws);
    const bool hoist    = ws_size >= used + 2 * NL * layerW + 1024;
    u16* w1 = (u16*)alloc(hoist ? NL * layerW : layerW);
    u16* w2 = (u16*)alloc(hoist ? NL * layerW : layerW);

    embed_kernel<<<NTOK * 192 / 256, 256, 0, stream>>>(tokids, tok_emb, pos_emb, x);
    {
        const long na = (long)NL * 3 * DIM * DIM;
        const long nb = (long)NL * DIM * DIM;
        tobf16_2<<<(int)((na + nb) / 1024), 256, 0, stream>>>(in_w, inw16, out_w, outw16, na);
    }
    {
        const long total = (long)VOCAB * DIM;
        const int blocks = (int)((total / 4 + 255) / 256);
        dequant_kernel<<<blocks, 256, 0, stream>>>(head_idx, head_scale, lut, hw, total, DIM);
    }
    if (hoist) {
        const long t1 = (long)NL * HID * DIM;
        const long halfBlocks = t1 / 1024;
        dequant2_kernel<<<(int)(2 * halfBlocks), 256, 0, stream>>>(
            mlp1_idx, mlp1_scale, mlp2_idx, mlp2_scale, lut, w1, w2, halfBlocks);
    }

    for (int l = 0; l < NL; l++) {
        u16* w1l = hoist ? w1 + (size_t)l * HID * DIM : w1;
        u16* w2l = hoist ? w2 + (size_t)l * HID * DIM : w2;

        ln_kernel<<<NTOK / 4, 256, 0, stream>>>(x, ln1_g + l * DIM, ln1_b + l * DIM, h);
        gemm64<4, 1><<<dim3(NTOK / 64, 3 * DIM / 128), 256, 0, stream>>>(
            h, inw16 + (long)l * 3 * DIM * DIM, in_b + l * 3 * DIM, nullptr,
            qb, kb, vtb, NTOK, 3 * DIM, DIM, DIM);
        attn_kernel<<<dim3(BHB, 4), 256, 0, stream>>>(qb, kb, vtb, ob);
        // outproj: split-K=2, partials atomic-added into x (bias at z==0).
        gemm64<2, 5><<<dim3(NTOK / 64, DIM / 64, 2), 256, 0, stream>>>(
            ob, outw16 + (long)l * DIM * DIM, out_b + l * DIM, nullptr,
            x, nullptr, nullptr, NTOK, DIM, DIM / 2, DIM);
        ln_kernel<<<NTOK / 4, 256, 0, stream>>>(x, ln2_g + l * DIM, ln2_b + l * DIM, h);
        if (!hoist)
            dequant_kernel<<<HID * DIM / 1024, 256, 0, stream>>>(
                mlp1_idx + (long)l * HID * DIM, mlp1_scale + l * HID, lut, w1l, (long)HID * DIM, DIM);
        gemm64<4, 4><<<dim3(NTOK / 64, HID / 128), 256, 0, stream>>>(
            h, w1l, nullptr, nullptr, h2, nullptr, nullptr, NTOK, HID, DIM, DIM);
        if (!hoist)
            dequant_kernel<<<DIM * HID / 1024, 256, 0, stream>>>(
                mlp2_idx + (long)l * DIM * HID, mlp2_scale + l * DIM, lut, w2l, (long)DIM * HID, HID);
        // mlp2: split-K=2 (K=3072 -> 2x1536), partials atomic-added into x.
        gemm64<2, 5><<<dim3(NTOK / 64, DIM / 64, 2), 256, 0, stream>>>(
            h2, w2l, nullptr, nullptr, x, nullptr, nullptr, NTOK, DIM, HID / 2, HID);
    }

    ln_kernel<<<NTOK / 4, 256, 0, stream>>>(x, lnf_g, lnf_b, h);
    gemm_bt<4, 0><<<dim3(NTOK / 128, (VOCAB + 127) / 128, 1), 256, 0, stream>>>(
        h, hw, nullptr, nullptr, d_out, nullptr, nullptr, NTOK, VOCAB, DIM, 0, 0, 0);
}

// Round 12
// 2550.117 us; speedup vs baseline: 1.1415x; 1.0364x over previous
//
#include <hip/hip_runtime.h>
#include <stdint.h>

#define DIM 768
#define NL 13
#define NH 12
#define VOCAB 50257
#define SEQ 512
#define BATCH 4
#define HID 3072
#define HD 64
#define NTOK (BATCH*SEQ)   // 2048
#define BHB (BATCH*NH)     // 48 batched heads

typedef unsigned short u16;
typedef __attribute__((ext_vector_type(8))) __bf16 bf16x8;
typedef __attribute__((ext_vector_type(4))) float f32x4;

#define ASM_VMCNT(N) asm volatile("s_waitcnt vmcnt(" #N ")" ::: "memory")
#define ASM_LGKM0()  asm volatile("s_waitcnt lgkmcnt(0)" ::: "memory")

__device__ __forceinline__ u16 f2bf(float f) {
    union { float f; uint32_t u; } v; v.f = f;
    uint32_t u = v.u;
    return (u16)((u + 0x7FFFu + ((u >> 16) & 1u)) >> 16);   // RNE
}

__device__ __forceinline__ void gl2lds16(const void* g, void* l) {
    // async global->LDS, 16B/lane; LDS dest = wave-uniform base + lane*16
    __builtin_amdgcn_global_load_lds((const __attribute__((address_space(1))) void*)g,
                                     (__attribute__((address_space(3))) void*)l,
                                     16, 0, 0);
}

__device__ __forceinline__ float gelu_tanh(float x) {
    // tanh(y) = 1 - 2/(exp(2y)+1) via HW v_exp_f32 (no tanh instruction on gfx950)
    const float y = 0.7978845608028654f * (x + 0.044715f * x * x * x);
    const float t = 1.0f - 2.0f / (__expf(2.0f * y) + 1.0f);
    return 0.5f * x * (1.0f + t);
}

__device__ __forceinline__ void xcd_remap(int& bx, int& by) {
    const int gx = gridDim.x;
    const int nwg = gx * gridDim.y;
    const int orig = by * gx + bx;
    const int xcd = orig & 7;
    const int q = nwg >> 3, r = nwg & 7;
    const int wg = (xcd < r ? xcd * (q + 1) : r * (q + 1) + (xcd - r) * q) + (orig >> 3);
    bx = wg % gx; by = wg / gx;
}

// ---------------------------------------------------------------------------
// Shared epilogue.
// EPI: 0 plain f32 (col-bound checked), 1 qkv scatter, 3 f32 + bias + residual,
//      4 gelu -> bf16, 5 f32 atomic accumulate (split-K; resid pre-resident in
//      out0; bias added exactly once by the z==0 block)
// ---------------------------------------------------------------------------
template<int EPI>
__device__ __forceinline__ void epi_store(float v, int r, int c, int N, int z, long sC,
                                          const float* bias, const float* resid,
                                          void* out0, void* out1, void* out2)
{
    if constexpr (EPI == 0) {
        if (c < N) ((float*)out0)[(long)z * sC + (long)r * N + c] = v;
    } else if constexpr (EPI == 1) {
        v += bias[c];
        const int part = c / DIM;
        const int cc = c - part * DIM;
        const int hh = cc >> 6, d = cc & 63;
        const int b = r >> 9, t = r & 511;
        const int bh = b * NH + hh;
        if (part == 0)      ((u16*)out0)[((long)bh * SEQ + t) * HD + d] = f2bf(v);
        else if (part == 1) ((u16*)out1)[((long)bh * SEQ + t) * HD + d] = f2bf(v);
        else                ((u16*)out2)[((long)bh * HD + d) * SEQ + t] = f2bf(v);
    } else if constexpr (EPI == 3) {
        if (bias) v += bias[c];
        v += resid[(long)r * N + c];
        ((float*)out0)[(long)r * N + c] = v;
    } else if constexpr (EPI == 5) {
        if (bias && z == 0) v += bias[c];
        atomicAdd(&((float*)out0)[(long)r * N + c], v);
    } else {
        ((u16*)out0)[(long)r * N + c] = f2bf(gelu_tanh(v));
    }
}

// ---------------------------------------------------------------------------
// Head GEMM: 128 x (WN*32) tile, BK=32, depth-2 counted-vmcnt pipeline.
// WN=4 kept: m112 measured 128^2 (912 TF) > 128x256 (823) at this structure.
// ---------------------------------------------------------------------------
template<int WN, int EPI>
__global__ __launch_bounds__(256)
void gemm_bt(const u16* __restrict__ A, const u16* __restrict__ B,
             const float* __restrict__ bias, const float* __restrict__ resid,
             void* __restrict__ out0, void* __restrict__ out1, void* __restrict__ out2,
             int M, int N, int K, long sA, long sB, long sC)
{
    constexpr int TN = WN * 32;
    constexpr int NBG = TN / 64;                   // B staging groups of 64 rows
    __shared__ __align__(16) u16 As[2 * 128 * 32];
    __shared__ __align__(16) u16 Bs[2 * TN * 32];

    const int tid  = threadIdx.x;
    const int wave = tid >> 6;
    const int lane = tid & 63;
    const int quad = lane >> 4;
    const int l16  = lane & 15;
    const int wm   = wave >> 1;
    const int wn   = wave & 1;

    int bx = blockIdx.x, by = blockIdx.y;
    xcd_remap(bx, by);

    const int m0 = bx * 128;
    const int n0 = by * TN;
    const int z  = blockIdx.z;

    const u16* Ab = A + (long)z * sA;
    const u16* Bb = B + (long)z * sB;

    const int srow = tid >> 2;          // 0..63
    const int scol = ((tid & 3) ^ ((srow >> 1) & 3)) * 8;   // pre-swizzled k-chunk

    const long aoff0 = (long)(m0 + srow) * K + scol;
    const long aoff1 = (long)(m0 + 64 + srow) * K + scol;
    long boff[NBG];
    #pragma unroll
    for (int g = 0; g < NBG; g++) {
        int br = n0 + g * 64 + srow; if (br > N - 1) br = N - 1;
        boff[g] = (long)br * K + scol;
    }

    auto stage = [&](int b, int k0) {
        gl2lds16(Ab + aoff0 + k0, As + b * 4096 + wave * 512);
        gl2lds16(Ab + aoff1 + k0, As + b * 4096 + 2048 + wave * 512);
        #pragma unroll
        for (int g = 0; g < NBG; g++)
            gl2lds16(Bb + boff[g] + k0, Bs + b * (TN * 32) + g * 2048 + wave * 512);
    };

    f32x4 acc[4][WN];
    #pragma unroll
    for (int i = 0; i < 4; i++)
        #pragma unroll
        for (int j = 0; j < WN; j++)
            acc[i][j] = (f32x4){0.f, 0.f, 0.f, 0.f};

    const int sq8 = (quad ^ ((l16 >> 1) & 3)) * 8;
    const int arow = (wm * 64 + l16) * 32 + sq8;
    const int brow = (wn * (WN * 16) + l16) * 32 + sq8;

    stage(0, 0);
    if (K > 32) stage(1, 32);

    int cur = 0;
    for (int k0 = 0; k0 < K; k0 += 32) {
        // land step k0's loads; step k0+32's (4 newest) may stay in flight
        if (k0 + 32 < K) ASM_VMCNT(4); else ASM_VMCNT(0);
        __builtin_amdgcn_s_barrier();

        const u16* Ar = As + cur * 4096;
        const u16* Br = Bs + cur * (TN * 32);
        bf16x8 af[4], bfr[WN];
        #pragma unroll
        for (int i = 0; i < 4; i++)
            af[i] = *(const bf16x8*)&Ar[arow + i * 512];
        #pragma unroll
        for (int j = 0; j < WN; j++)
            bfr[j] = *(const bf16x8*)&Br[brow + j * 512];
        ASM_LGKM0();                       // own reads done before signalling
        __builtin_amdgcn_s_barrier();      // all waves done reading buf cur
        if (k0 + 64 < K) stage(cur, k0 + 64);   // restage 2 steps ahead

        #pragma unroll
        for (int i = 0; i < 4; i++)
            #pragma unroll
            for (int j = 0; j < WN; j++)
                acc[i][j] = __builtin_amdgcn_mfma_f32_16x16x32_bf16(af[i], bfr[j], acc[i][j], 0, 0, 0);

        cur ^= 1;
    }

    const int rbase = m0 + wm * 64;
    const int cbase = n0 + wn * (WN * 16);
    #pragma unroll
    for (int i = 0; i < 4; i++)
        #pragma unroll
        for (int j = 0; j < WN; j++)
            #pragma unroll
            for (int rg = 0; rg < 4; rg++)
                epi_store<EPI>(acc[i][j][rg], rbase + i * 16 + quad * 4 + rg,
                               cbase + j * 16 + l16, N, z, sC, bias, resid, out0, out1, out2);
}

// ---------------------------------------------------------------------------
// Layer GEMM: 64 x (WN*32) tile, BK=64, depth-2 counted-vmcnt pipeline.
// Split-K via blockIdx.z (EPI=5 atomic accumulate, bias at z==0).
// Requires M%64==0, N%TN==0, K%64==0.
// ---------------------------------------------------------------------------
template<int WN, int EPI>
__global__ __launch_bounds__(256)
void gemm64(const u16* __restrict__ A, const u16* __restrict__ B,
            const float* __restrict__ bias, const float* __restrict__ resid,
            void* __restrict__ out0, void* __restrict__ out1, void* __restrict__ out2,
            int M, int N, int K, int Kstride)
{
    constexpr int TN = WN * 32;
    constexpr int NC = TN / 32;                    // B staging sub-blocks of 32 rows
    __shared__ __align__(16) u16 As[2 * 64 * 64];  // 16 KB
    __shared__ __align__(16) u16 Bs[2 * TN * 64];  // 32 or 16 KB

    const int tid  = threadIdx.x;
    const int wave = tid >> 6;
    const int lane = tid & 63;
    const int quad = lane >> 4;
    const int l16  = lane & 15;
    const int wm   = wave >> 1;
    const int wn   = wave & 1;

    int bx = blockIdx.x, by = blockIdx.y;
    xcd_remap(bx, by);
    const int m0 = bx * 64;
    const int n0 = by * TN;
    const int koff = blockIdx.z * K;

    // staging geometry: row = c*32 + (tid>>3), chunk = tid&7 (8 elems / 16 B)
    const int srow = tid >> 3;                       // 0..31
    const int sch  = ((tid & 7) ^ (srow & 7)) * 8;   // swizzled chunk (elems)
    u16* const asw = As + wave * 512;                // wave*8 rows * 64
    u16* const bsw = Bs + wave * 512;

    const long aoff = (long)(m0 + srow) * Kstride + koff + sch;
    const long boff = (long)(n0 + srow) * Kstride + koff + sch;

    auto stageA = [&](int b, int k0) {
        #pragma unroll
        for (int c = 0; c < 2; c++)
            gl2lds16(A + aoff + (long)c * 32 * Kstride + k0, asw + b * 4096 + c * 2048);
    };
    auto stageB = [&](int b, int k0) {
        #pragma unroll
        for (int c = 0; c < NC; c++)
            gl2lds16(B + boff + (long)c * 32 * Kstride + k0, bsw + b * TN * 64 + c * 2048);
    };

    f32x4 acc[2][WN];
    #pragma unroll
    for (int i = 0; i < 2; i++)
        #pragma unroll
        for (int j = 0; j < WN; j++)
            acc[i][j] = (f32x4){0.f, 0.f, 0.f, 0.f};

    const int rsw = l16 & 7;   // frag read swizzle: row&7 == l16&7

    stageA(0, 0); stageB(0, 0);
    if (K > 64) { stageA(1, 64); stageB(1, 64); }

    int cur = 0;
    for (int k0 = 0; k0 < K; k0 += 64) {
        if (k0 + 64 < K) { if constexpr (NC == 4) ASM_VMCNT(6); else ASM_VMCNT(4); }
        else ASM_VMCNT(0);
        __builtin_amdgcn_s_barrier();

        const u16* Ar = As + cur * 4096;
        const u16* Br = Bs + cur * TN * 64;
        bf16x8 af[2][2], bfr[WN][2];
        #pragma unroll
        for (int i = 0; i < 2; i++)
            #pragma unroll
            for (int kk = 0; kk < 2; kk++)
                af[i][kk] = *(const bf16x8*)&Ar[(wm * 32 + i * 16 + l16) * 64 + (((kk * 4 + quad) ^ rsw) * 8)];
        #pragma unroll
        for (int j = 0; j < WN; j++)
            #pragma unroll
            for (int kk = 0; kk < 2; kk++)
                bfr[j][kk] = *(const bf16x8*)&Br[(wn * (WN * 16) + j * 16 + l16) * 64 + (((kk * 4 + quad) ^ rsw) * 8)];
        ASM_LGKM0();
        __builtin_amdgcn_s_barrier();
        if (k0 + 128 < K) { stageA(cur, k0 + 128); stageB(cur, k0 + 128); }

        #pragma unroll
        for (int kk = 0; kk < 2; kk++)
            #pragma unroll
            for (int i = 0; i < 2; i++)
                #pragma unroll
                for (int j = 0; j < WN; j++)
                    acc[i][j] = __builtin_amdgcn_mfma_f32_16x16x32_bf16(af[i][kk], bfr[j][kk], acc[i][j], 0, 0, 0);

        cur ^= 1;
    }

    const int rbase = m0 + wm * 32;
    const int cbase = n0 + wn * (WN * 16);
    #pragma unroll
    for (int i = 0; i < 2; i++)
        #pragma unroll
        for (int j = 0; j < WN; j++)
            #pragma unroll
            for (int rg = 0; rg < 4; rg++)
                epi_store<EPI>(acc[i][j][rg], rbase + i * 16 + quad * 4 + rg,
                               cbase + j * 16 + l16, N, (int)blockIdx.z, 0,
                               bias, resid, out0, out1, out2);
}

// ---------------------------------------------------------------------------
// Fused flash attention — exact round-9 structure (best measured): 256 threads,
// grid (BHB,4), 4 waves of 32 q-rows, K/V staged to LDS with XOR-chunk swizzle,
// unconditional online-softmax rescale.  ONE delta vs r9: the K staging loop is
// fully unrolled with a BLOCK-UNIFORM guard (cI*32 < nkv, nkv multiple of 128)
// — skips the causally-unneeded stage calls at pure-SALU cost (avg -37%).
// ---------------------------------------------------------------------------
__global__ __launch_bounds__(256)
void attn_kernel(const u16* __restrict__ qb, const u16* __restrict__ kb,
                 const u16* __restrict__ vtb, u16* __restrict__ ob)
{
    __shared__ __align__(16) u16 Ks[512 * 64];     // 64KB  [kv][d] (first nkv rows used)
    __shared__ __align__(16) u16 Vs[64 * 512];     // 64KB  [d][kv] (V^T)
    __shared__ __align__(16) u16 Ps[4][32 * 64];   // 16KB  per-wave P tile

    const int tid  = threadIdx.x;
    const int wave = tid >> 6;
    const int lane = tid & 63;
    const int quad = lane >> 4;
    const int l16  = lane & 15;

    const int bh   = blockIdx.x;
    const int qblk = blockIdx.y;
    const int qr0  = qblk * 128 + wave * 32;
    const int nkv  = (qblk + 1) * 128;   // causal K range for this block

    #pragma unroll
    for (int cI = 0; cI < 16; ++cI) {
        if (cI * 32 < nkv) {             // block-uniform guard (nkv % 128 == 0)
            const int rbase = cI * 32 + wave * 8;
            const int r  = rbase + (lane >> 3);
            const int ch = lane & 7;
            gl2lds16(kb + ((long)bh * SEQ + r) * HD + ((ch ^ (r & 7)) * 8), Ks + rbase * 64);
        }
    }
    #pragma unroll 4
    for (int cI = 0; cI < 16; ++cI) {
        const int d = cI * 4 + wave;
        gl2lds16(vtb + ((long)bh * HD + d) * SEQ + ((lane ^ (d & 7)) * 8), Vs + d * 512);
    }

    bf16x8 af[2][2];
    const long qoff = ((long)bh * SEQ + qr0) * HD;
    #pragma unroll
    for (int i = 0; i < 2; i++)
        #pragma unroll
        for (int kc = 0; kc < 2; kc++)
            af[i][kc] = *(const bf16x8*)&qb[qoff + (long)(i * 16 + l16) * HD + kc * 32 + quad * 8];

    __syncthreads();   // drains vmcnt for the LDS staging

    f32x4 o[2][4];
    float mrun[2][4], lrun[2][4];
    #pragma unroll
    for (int i = 0; i < 2; i++)
        #pragma unroll
        for (int rg = 0; rg < 4; rg++) { mrun[i][rg] = -1e30f; lrun[i][rg] = 0.f; }
    #pragma unroll
    for (int i = 0; i < 2; i++)
        #pragma unroll
        for (int nd = 0; nd < 4; nd++)
            o[i][nd] = (f32x4){0.f, 0.f, 0.f, 0.f};

    u16* const Pw = &Ps[wave][0];
    const int rsw = l16 & 7;
    const int kvend = qr0 + 32;

    for (int kv0 = 0; kv0 < kvend; kv0 += 64) {
        f32x4 s[2][4];
        #pragma unroll
        for (int i = 0; i < 2; i++)
            #pragma unroll
            for (int n = 0; n < 4; n++)
                s[i][n] = (f32x4){0.f, 0.f, 0.f, 0.f};
        bf16x8 bf[4][2];
        #pragma unroll
        for (int n = 0; n < 4; n++)
            #pragma unroll
            for (int kc = 0; kc < 2; kc++)
                bf[n][kc] = *(const bf16x8*)&Ks[(kv0 + n * 16 + l16) * 64 + (((kc * 4 + quad) ^ rsw) * 8)];
        #pragma unroll
        for (int i = 0; i < 2; i++)
            #pragma unroll
            for (int n = 0; n < 4; n++)
                #pragma unroll
                for (int kc = 0; kc < 2; kc++)
                    s[i][n] = __builtin_amdgcn_mfma_f32_16x16x32_bf16(af[i][kc], bf[n][kc], s[i][n], 0, 0, 0);

        #pragma unroll
        for (int i = 0; i < 2; i++) {
            #pragma unroll
            for (int rg = 0; rg < 4; rg++) {
                const int q = qr0 + i * 16 + quad * 4 + rg;
                float v[4];
                #pragma unroll
                for (int n = 0; n < 4; n++) {
                    const int c = kv0 + n * 16 + l16;
                    v[n] = (c <= q) ? s[i][n][rg] * 0.125f : -1e30f;
                }
                float pm = fmaxf(fmaxf(v[0], v[1]), fmaxf(v[2], v[3]));
                #pragma unroll
                for (int off = 1; off < 16; off <<= 1) pm = fmaxf(pm, __shfl_xor(pm, off));
                const float mo = mrun[i][rg];
                const float mn = fmaxf(mo, pm);
                const float corr = __expf(mo - mn);
                float ps = 0.f;
                #pragma unroll
                for (int n = 0; n < 4; n++) { const float e = __expf(v[n] - mn); v[n] = e; ps += e; }
                #pragma unroll
                for (int off = 1; off < 16; off <<= 1) ps += __shfl_xor(ps, off);
                lrun[i][rg] = lrun[i][rg] * corr + ps;
                mrun[i][rg] = mn;
                #pragma unroll
                for (int nd = 0; nd < 4; nd++) o[i][nd][rg] *= corr;
                const int qlz = i * 16 + quad * 4 + rg;
                const int sw = qlz & 7;
                #pragma unroll
                for (int n = 0; n < 4; n++)
                    Pw[qlz * 64 + (((n * 2 + (l16 >> 3)) ^ sw) * 8) + (l16 & 7)] = f2bf(v[n]);
            }
        }
        asm volatile("s_waitcnt lgkmcnt(0)" ::: "memory");   // P writes visible wave-wide

        bf16x8 pa[2][2], vb[4][2];
        #pragma unroll
        for (int i = 0; i < 2; i++)
            #pragma unroll
            for (int kc = 0; kc < 2; kc++)
                pa[i][kc] = *(const bf16x8*)&Pw[(i * 16 + l16) * 64 + (((kc * 4 + quad) ^ rsw) * 8)];
        #pragma unroll
        for (int nd = 0; nd < 4; nd++)
            #pragma unroll
            for (int kc = 0; kc < 2; kc++)
                vb[nd][kc] = *(const bf16x8*)&Vs[(nd * 16 + l16) * 512 + ((((kv0 >> 3) + kc * 4 + quad) ^ rsw) * 8)];
        #pragma unroll
        for (int i = 0; i < 2; i++)
            #pragma unroll
            for (int nd = 0; nd < 4; nd++)
                #pragma unroll
                for (int kc = 0; kc < 2; kc++)
                    o[i][nd] = __builtin_amdgcn_mfma_f32_16x16x32_bf16(pa[i][kc], vb[nd][kc], o[i][nd], 0, 0, 0);
    }

    const int b  = bh / NH, hh = bh - b * NH;
    #pragma unroll
    for (int i = 0; i < 2; i++) {
        #pragma unroll
        for (int rg = 0; rg < 4; rg++) {
            const float inv = 1.f / lrun[i][rg];
            const int t = qr0 + i * 16 + quad * 4 + rg;
            u16* orow = ob + ((long)(b * SEQ + t)) * DIM + hh * HD;
            #pragma unroll
            for (int nd = 0; nd < 4; nd++)
                orow[nd * 16 + l16] = f2bf(o[i][nd][rg] * inv);
        }
    }
}

// x = tok_emb[idx] + pos_emb ; fp32 out
__global__ __launch_bounds__(256)
void embed_kernel(const int* __restrict__ tokidx, const float* __restrict__ tok,
                  const float* __restrict__ pos, float* __restrict__ x)
{
    const int i = blockIdx.x * 256 + threadIdx.x;   // float4 index over NTOK*192
    const int row = i / 192;
    const int c4 = i - row * 192;
    const int t = row & (SEQ - 1);
    const int tk = tokidx[row];
    const float4 a = *(const float4*)&tok[(long)tk * DIM + c4 * 4];
    const float4 p = *(const float4*)&pos[(long)t * DIM + c4 * 4];
    *(float4*)&x[(long)row * DIM + c4 * 4] = make_float4(a.x + p.x, a.y + p.y, a.z + p.z, a.w + p.w);
}

// LayerNorm over DIM=768, one wave per row, bf16 out
__global__ __launch_bounds__(256)
void ln_kernel(const float* __restrict__ x, const float* __restrict__ g,
               const float* __restrict__ b, u16* __restrict__ out)
{
    const int row = blockIdx.x * 4 + (threadIdx.x >> 6);
    const int lane = threadIdx.x & 63;
    const float* xr = x + (long)row * DIM;
    float v[12];
    float s = 0.f, s2 = 0.f;
    #pragma unroll
    for (int i = 0; i < 3; i++) {
        const float4 f = *(const float4*)&xr[i * 256 + lane * 4];
        v[i*4+0] = f.x; v[i*4+1] = f.y; v[i*4+2] = f.z; v[i*4+3] = f.w;
        s  += f.x + f.y + f.z + f.w;
        s2 += f.x*f.x + f.y*f.y + f.z*f.z + f.w*f.w;
    }
    for (int o = 32; o; o >>= 1) { s += __shfl_xor(s, o); s2 += __shfl_xor(s2, o); }
    const float m  = s * (1.f / DIM);
    const float var = s2 * (1.f / DIM) - m * m;
    const float rs = rsqrtf(var + 1e-5f);
    u16* orow = out + (long)row * DIM;
    #pragma unroll
    for (int i = 0; i < 3; i++) {
        const int c = i * 256 + lane * 4;
        ushort4 o4 = make_ushort4(
            f2bf((v[i*4+0] - m) * rs * g[c+0] + b[c+0]),
            f2bf((v[i*4+1] - m) * rs * g[c+1] + b[c+1]),
            f2bf((v[i*4+2] - m) * rs * g[c+2] + b[c+2]),
            f2bf((v[i*4+3] - m) * rs * g[c+3] + b[c+3]));
        *(ushort4*)&orow[c] = o4;
    }
}

// fused fp32 -> bf16 bulk convert over TWO buffers (a first, then b)
__global__ __launch_bounds__(256)
void tobf16_2(const float* __restrict__ a, u16* __restrict__ oa,
              const float* __restrict__ b, u16* __restrict__ ob, long na)
{
    long i = ((long)blockIdx.x * 256 + threadIdx.x) * 4;
    const float* src; u16* dst;
    if (i < na) { src = a; dst = oa; }
    else        { i -= na; src = b; dst = ob; }
    const float4 f = *(const float4*)&src[i];
    *(ushort4*)&dst[i] = make_ushort4(f2bf(f.x), f2bf(f.y), f2bf(f.z), f2bf(f.w));
}

// ghost dequant: w[o,k] = bf16(lut[idx[o,k]] * scale[o])
__global__ __launch_bounds__(256)
void dequant_kernel(const int* __restrict__ gidx, const float* __restrict__ scale,
                    const float* __restrict__ lut, u16* __restrict__ w,
                    long total, int Kd)
{
    __shared__ float slut[256];
    slut[threadIdx.x] = lut[threadIdx.x];
    __syncthreads();
    const long i4 = ((long)blockIdx.x * 256 + threadIdx.x) * 4;
    if (i4 >= total) return;
    const int4 g = *(const int4*)&gidx[i4];
    const float sc = scale[(int)(i4 / Kd)];
    *(ushort4*)&w[i4] = make_ushort4(f2bf(slut[g.x] * sc), f2bf(slut[g.y] * sc),
                                     f2bf(slut[g.z] * sc), f2bf(slut[g.w] * sc));
}

// fused ghost dequant for w1 (Kd=DIM) and w2 (Kd=HID): first halfBlocks blocks
// do w1, rest do w2.  Both sides are NL*HID*DIM elements.
__global__ __launch_bounds__(256)
void dequant2_kernel(const int* __restrict__ g1, const float* __restrict__ s1,
                     const int* __restrict__ g2, const float* __restrict__ s2,
                     const float* __restrict__ lut,
                     u16* __restrict__ w1, u16* __restrict__ w2, long halfBlocks)
{
    __shared__ float slut[256];
    slut[threadIdx.x] = lut[threadIdx.x];
    __syncthreads();
    const long bid = blockIdx.x;
    const int* g; const float* s; u16* w; int Kd; long i4;
    if (bid < halfBlocks) { g = g1; s = s1; w = w1; Kd = DIM; i4 = (bid * 256 + threadIdx.x) * 4; }
    else                  { g = g2; s = s2; w = w2; Kd = HID; i4 = ((bid - halfBlocks) * 256 + threadIdx.x) * 4; }
    const int4 q = *(const int4*)&g[i4];
    const float sc = s[(long)(i4 / Kd)];
    *(ushort4*)&w[i4] = make_ushort4(f2bf(slut[q.x] * sc), f2bf(slut[q.y] * sc),
                                     f2bf(slut[q.z] * sc), f2bf(slut[q.w] * sc));
}

extern "C" void kernel_launch(void* const* d_in, const int* in_sizes, int n_in,
                              void* d_out, int out_size, void* d_ws, size_t ws_size,
                              hipStream_t stream)
{
    const float* lut        = (const float*)d_in[0];
    const float* tok_emb    = (const float*)d_in[1];
    const float* pos_emb    = (const float*)d_in[2];
    const float* ln1_g      = (const float*)d_in[3];
    const float* ln1_b      = (const float*)d_in[4];
    const float* in_w       = (const float*)d_in[5];
    const float* in_b       = (const float*)d_in[6];
    const float* out_w      = (const float*)d_in[7];
    const float* out_b      = (const float*)d_in[8];
    const float* ln2_g      = (const float*)d_in[9];
    const float* ln2_b      = (const float*)d_in[10];
    const float* mlp1_scale = (const float*)d_in[11];
    const float* mlp2_scale = (const float*)d_in[12];
    const float* lnf_g      = (const float*)d_in[13];
    const float* lnf_b      = (const float*)d_in[14];
    const float* head_scale = (const float*)d_in[15];
    const int*   mlp1_idx   = (const int*)d_in[16];
    const int*   mlp2_idx   = (const int*)d_in[17];
    const int*   head_idx   = (const int*)d_in[18];
    const int*   tokids     = (const int*)d_in[19];

    char* p = (char*)d_ws;
    auto alloc = [&](size_t bytes) { char* r = p; p += (bytes + 255) & ~(size_t)255; return r; };
    float* x    = (float*)alloc((size_t)NTOK * DIM * 4);
    u16*  h     = (u16*) alloc((size_t)NTOK * DIM * 2);
    u16*  h2    = (u16*) alloc((size_t)NTOK * HID * 2);
    u16*  qb    = (u16*) alloc((size_t)BHB * SEQ * HD * 2);
    u16*  kb    = (u16*) alloc((size_t)BHB * SEQ * HD * 2);
    u16*  vtb   = (u16*) alloc((size_t)BHB * SEQ * HD * 2);
    u16*  ob    = (u16*) alloc((size_t)NTOK * DIM * 2);
    u16*  inw16 = (u16*) alloc((size_t)NL * 3 * DIM * DIM * 2);
    u16*  outw16= (u16*) alloc((size_t)NL * DIM * DIM * 2);
    u16*  hw    = (u16*) alloc((size_t)VOCAB * DIM * 2);

    // dequant hoist: all 13 layers of mlp1/mlp2 weights in the prologue, if
    // the workspace is big enough; else per-layer fallback.
    const size_t layerW = (size_t)HID * DIM * 2;          // 4.7 MB
    const size_t used   = (size_t)(p - (char*)d_ws);
    const bool hoist    = ws_size >= used + 2 * NL * layerW + 1024;
    u16* w1 = (u16*)alloc(hoist ? NL * layerW : layerW);
    u16* w2 = (u16*)alloc(hoist ? NL * layerW : layerW);

    embed_kernel<<<NTOK * 192 / 256, 256, 0, stream>>>(tokids, tok_emb, pos_emb, x);
    {
        const long na = (long)NL * 3 * DIM * DIM;
        const long nb = (long)NL * DIM * DIM;
        tobf16_2<<<(int)((na + nb) / 1024), 256, 0, stream>>>(in_w, inw16, out_w, outw16, na);
    }
    {
        const long total = (long)VOCAB * DIM;
        const int blocks = (int)((total / 4 + 255) / 256);
        dequant_kernel<<<blocks, 256, 0, stream>>>(head_idx, head_scale, lut, hw, total, DIM);
    }
    if (hoist) {
        const long t1 = (long)NL * HID * DIM;
        const long halfBlocks = t1 / 1024;
        dequant2_kernel<<<(int)(2 * halfBlocks), 256, 0, stream>>>(
            mlp1_idx, mlp1_scale, mlp2_idx, mlp2_scale, lut, w1, w2, halfBlocks);
    }

    for (int l = 0; l < NL; l++) {
        u16* w1l = hoist ? w1 + (size_t)l * HID * DIM : w1;
        u16* w2l = hoist ? w2 + (size_t)l * HID * DIM : w2;

        ln_kernel<<<NTOK / 4, 256, 0, stream>>>(x, ln1_g + l * DIM, ln1_b + l * DIM, h);
        gemm64<4, 1><<<dim3(NTOK / 64, 3 * DIM / 128), 256, 0, stream>>>(
            h, inw16 + (long)l * 3 * DIM * DIM, in_b + l * 3 * DIM, nullptr,
            qb, kb, vtb, NTOK, 3 * DIM, DIM, DIM);
        attn_kernel<<<dim3(BHB, 4), 256, 0, stream>>>(qb, kb, vtb, ob);
        // outproj: split-K=2, partials atomic-added into x (bias at z==0).
        gemm64<2, 5><<<dim3(NTOK / 64, DIM / 64, 2), 256, 0, stream>>>(
            ob, outw16 + (long)l * DIM * DIM, out_b + l * DIM, nullptr,
            x, nullptr, nullptr, NTOK, DIM, DIM / 2, DIM);
        ln_kernel<<<NTOK / 4, 256, 0, stream>>>(x, ln2_g + l * DIM, ln2_b + l * DIM, h);
        if (!hoist)
            dequant_kernel<<<HID * DIM / 1024, 256, 0, stream>>>(
                mlp1_idx + (long)l * HID * DIM, mlp1_scale + l * HID, lut, w1l, (long)HID * DIM, DIM);
        gemm64<4, 4><<<dim3(NTOK / 64, HID / 128), 256, 0, stream>>>(
            h, w1l, nullptr, nullptr, h2, nullptr, nullptr, NTOK, HID, DIM, DIM);
        if (!hoist)
            dequant_kernel<<<DIM * HID / 1024, 256, 0, stream>>>(
                mlp2_idx + (long)l * DIM * HID, mlp2_scale + l * DIM, lut, w2l, (long)DIM * HID, HID);
        // mlp2: split-K=2 (K=3072 -> 2x1536), partials atomic-added into x.
        gemm64<2, 5><<<dim3(NTOK / 64, DIM / 64, 2), 256, 0, stream>>>(
            h2, w2l, nullptr, nullptr, x, nullptr, nullptr, NTOK, DIM, HID / 2, HID);
    }

    ln_kernel<<<NTOK / 4, 256, 0, stream>>>(x, lnf_g, lnf_b, h);
    gemm_bt<4, 0><<<dim3(NTOK / 128, (VOCAB + 127) / 128, 1), 256, 0, stream>>>(
        h, hw, nullptr, nullptr, d_out, nullptr, nullptr, NTOK, VOCAB, DIM, 0, 0, 0);
}